// Round 3
// baseline (904.585 us; speedup 1.0000x reference)
//
#include <hip/hip_runtime.h>
#include <hip/hip_bf16.h>
#include <math.h>

typedef __attribute__((ext_vector_type(4))) float f32x4;
typedef __attribute__((ext_vector_type(8))) short s16x8;
typedef __attribute__((ext_vector_type(4))) unsigned short u16x4;
typedef __attribute__((ext_vector_type(2))) unsigned int u32x2;
typedef __attribute__((ext_vector_type(4))) unsigned int u32x4;

// B=16, L=512, D=512, H=8, DK=DV=64, TEMP=8
// ws layout (bf16 halves): qh[16][8][512][64] | kh same | vhT[16][8][64][512] | ofl[16][262144]
// each region 4,194,304 halves = 8 MB; total 32 MB of d_ws.

__device__ __forceinline__ unsigned short f2bf(float f) {
    unsigned int u = __builtin_bit_cast(unsigned int, f);
    u += 0x7fffu + ((u >> 16) & 1u);          // round-to-nearest-even
    return (unsigned short)(u >> 16);
}

// packed f32x2 -> bf16x2 (portable: 2x RTNE + pack; no inline asm)
__device__ __forceinline__ unsigned int cvtpk(float lo, float hi) {
    return (unsigned int)f2bf(lo) | ((unsigned int)f2bf(hi) << 16);
}

// ---------------- projections: qh/kh = X @ W^T + b  ([b][h][l][d] bf16),
// ---------------- v written TRANSPOSED directly: vhT [b][h][d][key] -----------------
__global__ __launch_bounds__(256) void proj_kernel(
    const float* __restrict__ q, const float* __restrict__ k, const float* __restrict__ v,
    const float* __restrict__ Wq, const float* __restrict__ bq,
    const float* __restrict__ Wk, const float* __restrict__ bk,
    const float* __restrict__ Wv, const float* __restrict__ bv,
    unsigned short* __restrict__ qh, unsigned short* __restrict__ kh, unsigned short* __restrict__ vhT)
{
    const int z = blockIdx.z;
    const float* X    = (z == 0) ? q  : (z == 1) ? k  : v;
    const float* W    = (z == 0) ? Wq : (z == 1) ? Wk : Wv;
    const float* bias = (z == 0) ? bq : (z == 1) ? bk : bv;
    unsigned short* out = (z == 0) ? qh : (z == 1) ? kh : vhT;

    __shared__ __align__(16) unsigned short lA[128 * 40];  // 128 rows, 32 halves + pad 8
    __shared__ __align__(16) unsigned short lB[128 * 40];

    const int t = threadIdx.x;
    const int m0 = blockIdx.x * 128;
    const int n0 = blockIdx.y * 128;
    const int wave = t >> 6, lane = t & 63, quad = lane >> 4, l16 = lane & 15;
    const int wm = (wave >> 1) * 64, wn = (wave & 1) * 64;

    f32x4 acc[4][4];
#pragma unroll
    for (int i = 0; i < 4; i++)
#pragma unroll
        for (int j = 0; j < 4; j++) acc[i][j] = (f32x4){0.f, 0.f, 0.f, 0.f};

    for (int k0 = 0; k0 < 512; k0 += 32) {
#pragma unroll
        for (int it = 0; it < 4; it++) {
            int idx = it * 256 + t;
            int row = idx >> 3, c = (idx & 7) * 4;
            f32x4 xa = *(const f32x4*)(X + (size_t)(m0 + row) * 512 + k0 + c);
            u32x2 pa = { cvtpk(xa.x, xa.y), cvtpk(xa.z, xa.w) };
            *(u32x2*)&lA[row * 40 + c] = pa;
            f32x4 xb = *(const f32x4*)(W + (size_t)(n0 + row) * 512 + k0 + c);
            u32x2 pb = { cvtpk(xb.x, xb.y), cvtpk(xb.z, xb.w) };
            *(u32x2*)&lB[row * 40 + c] = pb;
        }
        __syncthreads();
        s16x8 af[4], bm[4];
#pragma unroll
        for (int i = 0; i < 4; i++) af[i] = *(const s16x8*)&lA[(wm + i * 16 + l16) * 40 + quad * 8];
#pragma unroll
        for (int j = 0; j < 4; j++) bm[j] = *(const s16x8*)&lB[(wn + j * 16 + l16) * 40 + quad * 8];
#pragma unroll
        for (int i = 0; i < 4; i++)
#pragma unroll
            for (int j = 0; j < 4; j++)
                acc[i][j] = __builtin_amdgcn_mfma_f32_16x16x32_bf16(af[i], bm[j], acc[i][j], 0, 0, 0);
        __syncthreads();
    }
    // epilogue
    if (z == 2) {
        // v: write transposed vhT[b][h][d][key]; 4 consecutive keys per lane -> 8 B stores
#pragma unroll
        for (int j = 0; j < 4; j++) {
            int n = n0 + wn + j * 16 + l16;
            float bb = bias[n];
            int h = n >> 6, d = n & 63;
#pragma unroll
            for (int i = 0; i < 4; i++) {
                int m = m0 + wm + i * 16 + quad * 4;     // 4 consecutive l (no b crossing)
                int b = m >> 9, l = m & 511;
                u32x2 pk2 = { cvtpk(acc[i][j][0] + bb, acc[i][j][1] + bb),
                              cvtpk(acc[i][j][2] + bb, acc[i][j][3] + bb) };
                *(u32x2*)(out + (size_t)((b * 8 + h) * 64 + d) * 512 + l) = pk2;
            }
        }
    } else {
#pragma unroll
        for (int j = 0; j < 4; j++) {
            int n = n0 + wn + j * 16 + l16;
            float bb = bias[n];
            int h = n >> 6, d = n & 63;
#pragma unroll
            for (int i = 0; i < 4; i++) {
#pragma unroll
                for (int r = 0; r < 4; r++) {
                    int m = m0 + wm + i * 16 + quad * 4 + r;
                    int b = m >> 9, l = m & 511;
                    out[(size_t)((b * 8 + h) * 512 + l) * 64 + d] = f2bf(acc[i][j][r] + bb);
                }
            }
        }
    }
}

// ---------------- init output with bias -----------------
__global__ void init_out(float* __restrict__ out, const float* __restrict__ bf)
{
    int i = blockIdx.x * 256 + threadIdx.x;
    if (i < 8192) out[i] = bf[i & 511];
}

// ---------------- fused attention per (h,b,64 q rows) -----------------
// QK^T computed TRANSPOSED (A=K, B=Q): acc[tt][r] = S[key=tt*16+quad*4+r][q=l16-row]
// -> each lane owns 4 consecutive keys of ONE q-row: vector f32x4 attn stores,
//    8 B LDS P-writes, scalar softmax with 2 shuffles.
__global__ __launch_bounds__(256) void attn_kernel(
    const unsigned short* __restrict__ qh, const unsigned short* __restrict__ kh,
    const unsigned short* __restrict__ vhT,
    float* __restrict__ dout, unsigned short* __restrict__ ofl)
{
    __shared__ __align__(16) unsigned short lp[4][16][520];  // per-wave P tile [q][key], bf16
    const int bh = blockIdx.y;          // h*16 + b  (matches attn_flat row order h*B+b)
    const int h = bh >> 4, b = bh & 15;
    const int q0 = blockIdx.x * 64;
    const int t = threadIdx.x;
    const int w = t >> 6, lane = t & 63, quad = lane >> 4, l16 = lane & 15;
    const size_t base = (size_t)(b * 8 + h) * 32768;
    const unsigned short* qb = qh + base;
    const unsigned short* kb = kh + base;
    const unsigned short* vb = vhT + base;

    const int qrow = q0 + w * 16 + l16;
    s16x8 bq0 = *(const s16x8*)(qb + (size_t)qrow * 64 + quad * 8);       // B operand = Q rows
    s16x8 bq1 = *(const s16x8*)(qb + (size_t)qrow * 64 + 32 + quad * 8);

    f32x4 acc[32];
#pragma unroll
    for (int tt = 0; tt < 32; tt++) acc[tt] = (f32x4){0.f, 0.f, 0.f, 0.f};

    // scores^T: A = K rows, B = Q rows
    __builtin_amdgcn_s_setprio(1);
#pragma unroll
    for (int tt = 0; tt < 32; tt++) {
        const unsigned short* kp = kb + (size_t)(tt * 16 + l16) * 64 + quad * 8;
        s16x8 a0 = *(const s16x8*)kp;
        s16x8 a1 = *(const s16x8*)(kp + 32);
        acc[tt] = __builtin_amdgcn_mfma_f32_16x16x32_bf16(a0, bq0, acc[tt], 0, 0, 0);
        acc[tt] = __builtin_amdgcn_mfma_f32_16x16x32_bf16(a1, bq1, acc[tt], 0, 0, 0);
    }
    __builtin_amdgcn_s_setprio(0);

    // softmax over keys: lane holds 128 keys of q-row (l16); quads combined by 2 shuffles
    const float C1 = 0.18033688011112042f;   // log2(e) / 8  (temperature fold + exp2)
    float mx = -1e30f;
#pragma unroll
    for (int tt = 0; tt < 32; tt++)
#pragma unroll
        for (int r = 0; r < 4; r++) {
            float s = acc[tt][r] * C1;
            acc[tt][r] = s;
            mx = fmaxf(mx, s);
        }
    mx = fmaxf(mx, __shfl_xor(mx, 16));
    mx = fmaxf(mx, __shfl_xor(mx, 32));
    float sum = 0.f;
#pragma unroll
    for (int tt = 0; tt < 32; tt++)
#pragma unroll
        for (int r = 0; r < 4; r++) {
            float e = exp2f(acc[tt][r] - mx);   // native v_exp_f32 (exp2 is the HW op)
            acc[tt][r] = e;
            sum += e;
        }
    sum += __shfl_xor(sum, 16);
    sum += __shfl_xor(sum, 32);
    const float inv = 1.0f / sum;

    // attn fp32 out (streaming -> nontemporal, vector stores) + bf16 P to LDS
    float* rp = dout + 8192 + (size_t)bh * 262144 + (size_t)qrow * 512 + quad * 4;
#pragma unroll
    for (int tt = 0; tt < 32; tt++) {
        f32x4 p;
#pragma unroll
        for (int r = 0; r < 4; r++) p[r] = acc[tt][r] * inv;
        __builtin_nontemporal_store(p, (f32x4*)(rp + tt * 16));
        u32x2 pb = { cvtpk(p.x, p.y), cvtpk(p.z, p.w) };
        *(u32x2*)&lp[w][l16][tt * 16 + quad * 4] = pb;
    }
    // same-wave LDS RAW: DS ops execute in order within a wave, no barrier needed.

    // PV: out[q][d] = P @ V  (A = P rows (q), B = vhT rows (d))
    f32x4 oacc[4];
#pragma unroll
    for (int j = 0; j < 4; j++) oacc[j] = (f32x4){0.f, 0.f, 0.f, 0.f};
    __builtin_amdgcn_s_setprio(1);
#pragma unroll
    for (int ks = 0; ks < 16; ks++) {
        s16x8 pa = *(const s16x8*)&lp[w][l16][ks * 32 + quad * 8];
#pragma unroll
        for (int j = 0; j < 4; j++) {
            s16x8 bvv = *(const s16x8*)(vb + (size_t)(j * 16 + l16) * 512 + ks * 32 + quad * 8);
            oacc[j] = __builtin_amdgcn_mfma_f32_16x16x32_bf16(pa, bvv, oacc[j], 0, 0, 0);
        }
    }
    __builtin_amdgcn_s_setprio(0);
    // store out_flat bf16: ofl[b][(q*8+h)*64+d]  (re-read by fc -> keep cached, no nt)
#pragma unroll
    for (int j = 0; j < 4; j++) {
#pragma unroll
        for (int r = 0; r < 4; r++) {
            int qq = q0 + w * 16 + quad * 4 + r;
            int d = j * 16 + l16;
            ofl[(size_t)b * 262144 + (size_t)(qq * 8 + h) * 64 + d] = f2bf(oacc[j][r]);
        }
    }
}

// ---------------- dynamic fc: out[16,512] += ofl[16,262144] @ Wf^T -----------------
__global__ __launch_bounds__(512) void fc_kernel(
    const unsigned short* __restrict__ ofl, const float* __restrict__ Wf,
    float* __restrict__ out)
{
    __shared__ __align__(16) float red[8][4][64][4];  // 32 KB
    const int t = threadIdx.x;
    const int w = t >> 6, lane = t & 63, quad = lane >> 4, l16 = lane & 15;
    const int n0 = blockIdx.x * 64;
    const int kbase = blockIdx.y * 4096 + w * 512;

    f32x4 acc[4];
#pragma unroll
    for (int j = 0; j < 4; j++) acc[j] = (f32x4){0.f, 0.f, 0.f, 0.f};

#pragma unroll
    for (int ks = 0; ks < 16; ks++) {
        int kk = kbase + ks * 32;
        s16x8 af = *(const s16x8*)(ofl + (size_t)l16 * 262144 + kk + quad * 8);
#pragma unroll
        for (int j = 0; j < 4; j++) {
            const float* wp = Wf + (size_t)(n0 + j * 16 + l16) * 262144 + kk + quad * 8;
            f32x4 w0 = __builtin_nontemporal_load((const f32x4*)wp);      // Wf streamed once
            f32x4 w1 = __builtin_nontemporal_load((const f32x4*)wp + 1);
            u32x4 pw = { cvtpk(w0.x, w0.y), cvtpk(w0.z, w0.w),
                         cvtpk(w1.x, w1.y), cvtpk(w1.z, w1.w) };
            s16x8 bvv = __builtin_bit_cast(s16x8, pw);
            acc[j] = __builtin_amdgcn_mfma_f32_16x16x32_bf16(af, bvv, acc[j], 0, 0, 0);
        }
    }
#pragma unroll
    for (int j = 0; j < 4; j++) *(f32x4*)&red[w][j][lane][0] = acc[j];
    __syncthreads();
    if (t < 256) {
        int j = t >> 6, ln = t & 63;
        f32x4 s = (f32x4){0.f, 0.f, 0.f, 0.f};
#pragma unroll
        for (int wv = 0; wv < 8; wv++) s += *(const f32x4*)&red[wv][j][ln][0];
        int qd = ln >> 4, lo = ln & 15;
        int o = n0 + j * 16 + lo;
#pragma unroll
        for (int r = 0; r < 4; r++) atomicAdd(&out[(qd * 4 + r) * 512 + o], s[r]);
    }
}

extern "C" void kernel_launch(void* const* d_in, const int* in_sizes, int n_in,
                              void* d_out, int out_size, void* d_ws, size_t ws_size,
                              hipStream_t stream)
{
    const float* q  = (const float*)d_in[0];
    const float* k  = (const float*)d_in[1];
    const float* v  = (const float*)d_in[2];
    const float* Wq = (const float*)d_in[3];
    const float* bq = (const float*)d_in[4];
    const float* Wk = (const float*)d_in[5];
    const float* bk = (const float*)d_in[6];
    const float* Wv = (const float*)d_in[7];
    const float* bv = (const float*)d_in[8];
    const float* Wf = (const float*)d_in[9];
    const float* bf = (const float*)d_in[10];

    unsigned short* qh  = (unsigned short*)d_ws;
    unsigned short* kh  = qh  + 4194304;
    unsigned short* vhT = kh  + 4194304;
    unsigned short* ofl = vhT + 4194304;
    float* out = (float*)d_out;

    hipLaunchKernelGGL(proj_kernel, dim3(64, 4, 3), dim3(256), 0, stream,
                       q, k, v, Wq, bq, Wk, bk, Wv, bv, qh, kh, vhT);
    hipLaunchKernelGGL(init_out, dim3(32), dim3(256), 0, stream, out, bf);
    hipLaunchKernelGGL(attn_kernel, dim3(8, 128), dim3(256), 0, stream, qh, kh, vhT, out, ofl);
    hipLaunchKernelGGL(fc_kernel, dim3(8, 64), dim3(512), 0, stream, ofl, Wf, out);
}